// Round 1
// baseline (734.515 us; speedup 1.0000x reference)
//
#include <hip/hip_runtime.h>

#define NTOK 49
#define DIM 192
#define HEADS 6
#define HD 32

typedef __bf16 bf16x8 __attribute__((ext_vector_type(8)));
typedef float f32x4 __attribute__((ext_vector_type(4)));

// ws layout (bytes):
//   [0, 221184)        qkv_w bf16 frag-line layout (576 rows x 192, OT=36); q rows pre-scaled by 1/sqrt(32)
//   [221184, 294912)   proj_w bf16 frag layout (192 rows x 192, OT=12)
//   [294912, 393216)   bias_cd fp32 [6][16][64][4] in S^T C/D per-lane order
#define WPROJ_USH 110592
#define BIAS_BYTE 294912

#define SCALE 0.17677669529663687f   // 1/sqrt(32)

// native bf16 cast (RTNE on gfx950; m240: scalar cast is the fast path)
__device__ __forceinline__ unsigned int pack2(float a, float b) {
    unsigned short lo = __builtin_bit_cast(unsigned short, (__bf16)a);
    unsigned short hi = __builtin_bit_cast(unsigned short, (__bf16)b);
    return (unsigned int)lo | ((unsigned int)hi << 16);
}

__device__ __forceinline__ f32x4 mfma16(int4 a, int4 b, f32x4 c) {
    return __builtin_amdgcn_mfma_f32_16x16x32_bf16(
        __builtin_bit_cast(bf16x8, a), __builtin_bit_cast(bf16x8, b), c, 0, 0, 0);
}

// ---------- merged pre-kernel: weights + bias (unchanged layout) ----------
__global__ void prep(const float* __restrict__ qkv_w, const float* __restrict__ proj_w,
                     const float* __restrict__ bias_table, const int* __restrict__ rel_index,
                     unsigned short* __restrict__ w16, float* __restrict__ bias_cd) {
    int bid = blockIdx.x;
    if (bid < 72) {
        int c = bid * 256 + threadIdx.x;      // 16B chunk id, 0..18431
        const float* src; unsigned short* dst; int OT; int cc; int isq = 0;
        if (c < 13824)      { src = qkv_w;  dst = w16;             OT = 36; cc = c; isq = 1; }
        else                { src = proj_w; dst = w16 + WPROJ_USH; OT = 12; cc = c - 13824; }
        int lane = cc & 63;
        int t = cc >> 6;
        int ot = t % OT, ks = t / OT;
        int f  = ot * 16 + (lane & 15);
        int k0 = ks * 32 + (lane >> 4) * 8;
        float sc = (isq && f < 192) ? SCALE : 1.0f;   // fold softmax scale into q weights
        const float* p = src + (size_t)f * DIM + k0;
        float4 a = *(const float4*)p;
        float4 b = *(const float4*)(p + 4);
        uint4 o;
        o.x = pack2(a.x * sc, a.y * sc); o.y = pack2(a.z * sc, a.w * sc);
        o.z = pack2(b.x * sc, b.y * sc); o.w = pack2(b.z * sc, b.w * sc);
        *(uint4*)(dst + (size_t)cc * 8) = o;
    } else {
        int gid = (bid - 72) * 256 + threadIdx.x;     // 0..6143
        int lane = gid & 63;
        int tile = (gid >> 6) & 15;
        int h    = gid >> 10;
        int kt = tile >> 2, qt = tile & 3;            // S^T tile: m=key tile kt, n=qtok tile qt
        int qtok = qt * 16 + (lane & 15);
        int key0 = kt * 16 + (lane >> 4) * 4;
        float4 v;
        float* vp = (float*)&v;
        for (int r = 0; r < 4; ++r) {
            int key = key0 + r;
            float val;
            if (key >= NTOK)       val = -1e30f;      // padded key row -> softmax 0
            else if (qtok >= NTOK) val = 0.0f;        // padded query col: don't care
            else                   val = bias_table[rel_index[qtok * NTOK + key] * HEADS + h];
            vp[r] = val;
        }
        *(float4*)(bias_cd + (size_t)gid * 4) = v;
    }
}

// ---------- main fused kernel: one workgroup per window, wave = head ----------
// LDS 30 KB: xs [0,24K) persistent until v-pass done; per-head 1K scratch at
// 24K + h*1K, reused SEQUENTIALLY at 1KB-tile granularity (in-wave DS is
// in-order). O (24K) overlays xs after B1a.
// Register discipline: q-pass(32 acc) -> qf, k-pass(32 acc, reuses) -> kf,
// per-qt streamed softmax (8 live S regs), v-pass(32 acc) -> vf, P2b.
// Peak unified VGPR+AGPR target <= 102 -> 3 blocks (18 waves) per CU.
#define SCR_OFF 24576
#define LDS_BYTES 30720

__global__ __launch_bounds__(384, 5) void win_attn(
    const float* __restrict__ x,
    const float* __restrict__ qkv_b,
    const float* __restrict__ proj_b,
    const unsigned short* __restrict__ wq16,
    const unsigned short* __restrict__ wp16,
    const float* __restrict__ bias_cd,
    float* __restrict__ out)
{
    extern __shared__ char smem[];
    const int tid  = threadIdx.x;
    const int lane = tid & 63;
    const int h    = tid >> 6;          // wave = head
    const int l15  = lane & 15;
    const int quad = lane >> 4;
    const int b    = blockIdx.x;

    // ---- Phase 0: stage x -> xs (bf16 frag-line layout, rows >=49 zero) ----
    #pragma unroll
    for (int i = 0; i < 4; ++i) {
        int c  = tid + i * 384;         // 1536 chunks = (ks*4+mt)*64 + cl
        int cl = c & 63;
        int mt = (c >> 6) & 3;
        int ks = c >> 8;
        int tok = mt * 16 + (cl & 15);
        int d0  = ks * 32 + (cl >> 4) * 8;
        uint4 o = {0u, 0u, 0u, 0u};
        if (tok < NTOK) {
            const float* p = x + ((size_t)b * NTOK + tok) * DIM + d0;
            float4 a  = *(const float4*)p;
            float4 bb = *(const float4*)(p + 4);
            o.x = pack2(a.x, a.y); o.y = pack2(a.z, a.w);
            o.z = pack2(bb.x, bb.y); o.w = pack2(bb.z, bb.w);
        }
        *(uint4*)(smem + (size_t)c * 16) = o;
    }
    __syncthreads();                                        // B0

    // hoisted address bases (immediate-offset ds_read / uniform weight bases)
    char* const xrd = smem + lane * 16;                     // + (ks*4+nt)*1024
    char* const buf = smem + SCR_OFF + h * 1024;            // 1KB per-head scratch
    char* const swr = buf + (quad & 1) * 8 + l15 * 16 + (quad >> 1) * 256;  // + slot*512
    char* const srd = buf + lane * 16;
    const unsigned short* const wqh = wq16 + (size_t)(h * 128 + lane) * 8;  // q:+ (ks*36+ft)*512, k:+6144, v:+12288
    const unsigned short* const wph = wp16 + (size_t)(h * 128 + lane) * 8;  // + (ks*12+j)*512

    // ---- q pass: C^T = Wq @ x^T (32 acc regs) ----
    int4 qf[4];
    {
        f32x4 qa[2][4];
        #pragma unroll
        for (int ft = 0; ft < 2; ++ft)
            #pragma unroll
            for (int nt = 0; nt < 4; ++nt) qa[ft][nt] = (f32x4){0,0,0,0};
        #pragma unroll
        for (int ks = 0; ks < 6; ++ks) {
            int4 wq[2];
            #pragma unroll
            for (int ft = 0; ft < 2; ++ft)
                wq[ft] = *(const int4*)(wqh + (ks*36 + ft) * 512);
            #pragma unroll
            for (int nt = 0; nt < 4; ++nt) {
                int4 xf = *(const int4*)(xrd + (ks*4 + nt) * 1024);
                #pragma unroll
                for (int ft = 0; ft < 2; ++ft)
                    qa[ft][nt] = mfma16(wq[ft], xf, qa[ft][nt]);
            }
        }
        float4 bq[2];
        #pragma unroll
        for (int ft = 0; ft < 2; ++ft) {
            float4 t = *(const float4*)(qkv_b + (h*2 + ft)*16 + quad*4);
            bq[ft].x = t.x*SCALE; bq[ft].y = t.y*SCALE; bq[ft].z = t.z*SCALE; bq[ft].w = t.w*SCALE;
        }
        // per-tile transpose through 1KB scratch: {2 st, 1 ld} per nt (in-order DS)
        #pragma unroll
        for (int nt = 0; nt < 4; ++nt) {
            #pragma unroll
            for (int ft = 0; ft < 2; ++ft) {
                uint2 w;
                w.x = pack2(qa[ft][nt][0] + bq[ft].x, qa[ft][nt][1] + bq[ft].y);
                w.y = pack2(qa[ft][nt][2] + bq[ft].z, qa[ft][nt][3] + bq[ft].w);
                *(uint2*)(swr + ft * 512) = w;
            }
            qf[nt] = *(const int4*)srd;
        }
    }

    // ---- k pass (reuses the 32 acc regs) ----
    int4 kf[4];
    {
        f32x4 ka[2][4];
        #pragma unroll
        for (int ft = 0; ft < 2; ++ft)
            #pragma unroll
            for (int nt = 0; nt < 4; ++nt) ka[ft][nt] = (f32x4){0,0,0,0};
        #pragma unroll
        for (int ks = 0; ks < 6; ++ks) {
            int4 wk[2];
            #pragma unroll
            for (int ft = 0; ft < 2; ++ft)
                wk[ft] = *(const int4*)(wqh + (ks*36 + ft) * 512 + 6144);
            #pragma unroll
            for (int nt = 0; nt < 4; ++nt) {
                int4 xf = *(const int4*)(xrd + (ks*4 + nt) * 1024);
                #pragma unroll
                for (int ft = 0; ft < 2; ++ft)
                    ka[ft][nt] = mfma16(wk[ft], xf, ka[ft][nt]);
            }
        }
        float4 bk[2];
        #pragma unroll
        for (int ft = 0; ft < 2; ++ft)
            bk[ft] = *(const float4*)(qkv_b + 192 + (h*2 + ft)*16 + quad*4);
        #pragma unroll
        for (int nt = 0; nt < 4; ++nt) {
            #pragma unroll
            for (int ft = 0; ft < 2; ++ft) {
                uint2 w;
                w.x = pack2(ka[ft][nt][0] + bk[ft].x, ka[ft][nt][1] + bk[ft].y);
                w.y = pack2(ka[ft][nt][2] + bk[ft].z, ka[ft][nt][3] + bk[ft].w);
                *(uint2*)(swr + ft * 512) = w;
            }
            kf[nt] = *(const int4*)srd;
        }
    }

    // ---- Phase 2a: S^T = k @ q^T + bias^T, streamed per qt (8 live S regs) ----
    float inv[4];
    int4 pf[2][4];
    const float* const bcb = bias_cd + (size_t)(h * 1024 + lane) * 4;  // + (kt*4+qt)*256 floats
    #pragma unroll
    for (int qt = 0; qt < 4; ++qt) {
        float sum = 0.f;
        #pragma unroll
        for (int ksn = 0; ksn < 2; ++ksn) {
            #pragma unroll
            for (int kt2 = 0; kt2 < 2; ++kt2) {
                const int kt = ksn*2 + kt2;
                f32x4 z = {0,0,0,0};
                f32x4 s = mfma16(kf[kt], qf[qt], z);
                float4 bc = *(const float4*)(bcb + (kt*4 + qt) * 256);
                // logits are O(1); padded keys carry -1e30 -> exp underflows to 0
                float e0 = __expf(s[0] + bc.x);
                float e1 = __expf(s[1] + bc.y);
                float e2 = __expf(s[2] + bc.z);
                float e3 = __expf(s[3] + bc.w);
                sum += (e0 + e1) + (e2 + e3);
                uint2 w;
                w.x = pack2(e0, e1);
                w.y = pack2(e2, e3);
                *(uint2*)(swr + kt2 * 512) = w;
            }
            pf[ksn][qt] = *(const int4*)srd;
        }
        sum += __shfl_xor(sum, 16);
        sum += __shfl_xor(sum, 32);
        inv[qt] = 1.0f / sum;                   // folded into O epilogue
    }

    // ---- v pass (32 acc regs; qf/kf dead) ----
    int4 vf[2][2];
    {
        f32x4 va[4][2];
        #pragma unroll
        for (int mt = 0; mt < 4; ++mt)
            #pragma unroll
            for (int nv = 0; nv < 2; ++nv) va[mt][nv] = (f32x4){0,0,0,0};
        #pragma unroll
        for (int ks = 0; ks < 6; ++ks) {
            int4 wv[2];
            #pragma unroll
            for (int nv = 0; nv < 2; ++nv)
                wv[nv] = *(const int4*)(wqh + (ks*36 + nv) * 512 + 12288);
            #pragma unroll
            for (int mt = 0; mt < 4; ++mt) {
                int4 xf = *(const int4*)(xrd + (ks*4 + mt) * 1024);
                #pragma unroll
                for (int nv = 0; nv < 2; ++nv)
                    va[mt][nv] = mfma16(xf, wv[nv], va[mt][nv]);
            }
        }
        const float bv0 = qkv_b[384 + h*32 + l15];
        const float bv1 = qkv_b[384 + h*32 + 16 + l15];
        #pragma unroll
        for (int ksn = 0; ksn < 2; ++ksn) {
            #pragma unroll
            for (int nv = 0; nv < 2; ++nv) {
                const float bv = nv ? bv1 : bv0;
                #pragma unroll
                for (int mt2 = 0; mt2 < 2; ++mt2) {
                    const int mt = ksn*2 + mt2;
                    uint2 w;
                    w.x = pack2(va[mt][nv][0] + bv, va[mt][nv][1] + bv);
                    w.y = pack2(va[mt][nv][2] + bv, va[mt][nv][3] + bv);
                    *(uint2*)(swr + mt2 * 512) = w;
                }
                vf[ksn][nv] = *(const int4*)srd;
            }
        }
    }

    // ---- Phase 2b: O^T = v^T @ P^T ----
    f32x4 oacc[2][4];                           // [dmt][qt]
    #pragma unroll
    for (int dmt = 0; dmt < 2; ++dmt)
        #pragma unroll
        for (int qt = 0; qt < 4; ++qt) oacc[dmt][qt] = (f32x4){0, 0, 0, 0};
    #pragma unroll
    for (int ksn = 0; ksn < 2; ++ksn)
        #pragma unroll
        for (int dmt = 0; dmt < 2; ++dmt)
            #pragma unroll
            for (int qt = 0; qt < 4; ++qt)
                oacc[dmt][qt] = mfma16(vf[ksn][dmt], pf[ksn][qt], oacc[dmt][qt]);
    __syncthreads();                                        // B1a: xs reads done everywhere

    // write O (normalized) as A-frags for proj, overlaying xs [0,24K)
    {
        char* const owr = smem + (quad & 1) * 8 + l15 * 16 + (quad >> 1) * 256;
        #pragma unroll
        for (int dmt = 0; dmt < 2; ++dmt) {
            #pragma unroll
            for (int qt = 0; qt < 4; ++qt) {
                uint2 w;
                w.x = pack2(oacc[dmt][qt][0] * inv[qt], oacc[dmt][qt][1] * inv[qt]);
                w.y = pack2(oacc[dmt][qt][2] * inv[qt], oacc[dmt][qt][3] * inv[qt]);
                *(uint2*)(owr + (h*4 + qt) * 1024 + dmt * 512) = w;
            }
        }
    }
    __syncthreads();                                        // B1b

    // ---- Phase 3: out = O @ proj_w^T + proj_b ----
    {
        f32x4 acc[4][2];
        #pragma unroll
        for (int mt = 0; mt < 4; ++mt)
            #pragma unroll
            for (int j = 0; j < 2; ++j) acc[mt][j] = (f32x4){0, 0, 0, 0};
        #pragma unroll
        for (int ks = 0; ks < 6; ++ks) {
            int4 wb[2];
            #pragma unroll
            for (int j = 0; j < 2; ++j)
                wb[j] = *(const int4*)(wph + (ks*12 + j) * 512);
            #pragma unroll
            for (int mt = 0; mt < 4; ++mt) {
                int4 oa = *(const int4*)(xrd + (ks*4 + mt) * 1024);
                #pragma unroll
                for (int j = 0; j < 2; ++j)
                    acc[mt][j] = mfma16(oa, wb[j], acc[mt][j]);
            }
        }
        #pragma unroll
        for (int j = 0; j < 2; ++j) {
            const int o = (h*2 + j) * 16 + l15;
            const float pb = proj_b[o];
            #pragma unroll
            for (int mt = 0; mt < 4; ++mt) {
                const int t0 = mt * 16 + quad * 4;
                #pragma unroll
                for (int r = 0; r < 4; ++r) {
                    const int t = t0 + r;
                    if (t < NTOK)
                        out[((size_t)b * NTOK + t) * DIM + o] = acc[mt][j][r] + pb;
                }
            }
        }
    }
}

extern "C" void kernel_launch(void* const* d_in, const int* in_sizes, int n_in,
                              void* d_out, int out_size, void* d_ws, size_t ws_size,
                              hipStream_t stream) {
    const float* x          = (const float*)d_in[0];
    const float* qkv_w      = (const float*)d_in[1];
    const float* qkv_b      = (const float*)d_in[2];
    const float* proj_w     = (const float*)d_in[3];
    const float* proj_b     = (const float*)d_in[4];
    const float* bias_table = (const float*)d_in[5];
    const int*   rel_index  = (const int*)d_in[6];
    float* out = (float*)d_out;

    unsigned short* w16 = (unsigned short*)d_ws;
    float* bias_cd = (float*)((char*)d_ws + BIAS_BYTE);

    prep<<<96, 256, 0, stream>>>(qkv_w, proj_w, bias_table, rel_index, w16, bias_cd);

    (void)hipFuncSetAttribute((const void*)win_attn,
                              hipFuncAttributeMaxDynamicSharedMemorySize, LDS_BYTES);
    win_attn<<<4096, 384, LDS_BYTES, stream>>>(x, qkv_b, proj_b,
                                               w16, w16 + WPROJ_USH, bias_cd, out);
}

// Round 2
// 678.104 us; speedup vs baseline: 1.0832x; 1.0832x over previous
//
#include <hip/hip_runtime.h>

#define NTOK 49
#define DIM 192
#define HEADS 6

typedef __bf16 bf16x8 __attribute__((ext_vector_type(8)));
typedef float f32x4 __attribute__((ext_vector_type(4)));

// ws layout (bytes):
//   [0, 221184)        qkv_w bf16 frag-line layout (576 rows x 192, OT=36); q rows pre-scaled by 1/sqrt(32)
//   [221184, 294912)   proj_w bf16 frag layout (192 rows x 192, OT=12)
//   [294912, 393216)   bias_cd fp32 [6][16][64][4] in S^T C/D per-lane order
#define WPROJ_USH 110592
#define BIAS_BYTE 294912

#define SCALE 0.17677669529663687f   // 1/sqrt(32)

// O parking: window w's O lives in d_out's own slice: bytes [w*37632, w*37632+24576)
// as 24 bf16 A-frag lines of 1KB: line index (h*4 + qt), content = 64 lanes x 16B.
#define OUT_WIN_BYTES 37632          // 49*192*4

__device__ __forceinline__ unsigned int pack2(float a, float b) {
    unsigned short lo = __builtin_bit_cast(unsigned short, (__bf16)a);
    unsigned short hi = __builtin_bit_cast(unsigned short, (__bf16)b);
    return (unsigned int)lo | ((unsigned int)hi << 16);
}

__device__ __forceinline__ f32x4 mfma16(int4 a, int4 b, f32x4 c) {
    return __builtin_amdgcn_mfma_f32_16x16x32_bf16(
        __builtin_bit_cast(bf16x8, a), __builtin_bit_cast(bf16x8, b), c, 0, 0, 0);
}

// ---------- merged pre-kernel: weights + bias (unchanged layout) ----------
__global__ void prep(const float* __restrict__ qkv_w, const float* __restrict__ proj_w,
                     const float* __restrict__ bias_table, const int* __restrict__ rel_index,
                     unsigned short* __restrict__ w16, float* __restrict__ bias_cd) {
    int bid = blockIdx.x;
    if (bid < 72) {
        int c = bid * 256 + threadIdx.x;      // 16B chunk id, 0..18431
        const float* src; unsigned short* dst; int OT; int cc; int isq = 0;
        if (c < 13824)      { src = qkv_w;  dst = w16;             OT = 36; cc = c; isq = 1; }
        else                { src = proj_w; dst = w16 + WPROJ_USH; OT = 12; cc = c - 13824; }
        int lane = cc & 63;
        int t = cc >> 6;
        int ot = t % OT, ks = t / OT;
        int f  = ot * 16 + (lane & 15);
        int k0 = ks * 32 + (lane >> 4) * 8;
        float sc = (isq && f < 192) ? SCALE : 1.0f;   // fold softmax scale into q weights
        const float* p = src + (size_t)f * DIM + k0;
        float4 a = *(const float4*)p;
        float4 b = *(const float4*)(p + 4);
        uint4 o;
        o.x = pack2(a.x * sc, a.y * sc); o.y = pack2(a.z * sc, a.w * sc);
        o.z = pack2(b.x * sc, b.y * sc); o.w = pack2(b.z * sc, b.w * sc);
        *(uint4*)(dst + (size_t)cc * 8) = o;
    } else {
        int gid = (bid - 72) * 256 + threadIdx.x;     // 0..6143
        int lane = gid & 63;
        int tile = (gid >> 6) & 15;
        int h    = gid >> 10;
        int kt = tile >> 2, qt = tile & 3;            // S^T tile: m=key tile kt, n=qtok tile qt
        int qtok = qt * 16 + (lane & 15);
        int key0 = kt * 16 + (lane >> 4) * 4;
        float4 v;
        float* vp = (float*)&v;
        for (int r = 0; r < 4; ++r) {
            int key = key0 + r;
            float val;
            if (key >= NTOK)       val = -1e30f;      // padded key row -> softmax 0
            else if (qtok >= NTOK) val = 0.0f;        // padded query col: don't care
            else                   val = bias_table[rel_index[qtok * NTOK + key] * HEADS + h];
            vp[r] = val;
        }
        *(float4*)(bias_cd + (size_t)gid * 4) = v;
    }
}

// ---------- K1: attention. 2 blocks per window, 3 waves (= 3 heads) each ----------
// LDS 27 KB: xs [0,24K) + per-wave 1KB scratch. ONE barrier; waves independent after.
// O written straight to global (window's own out slice) as bf16 A-frag lines.
// Register peak ~100 unified -> (192,4)=128 budget, spill-free; 5 blocks/CU by LDS.
#define SCR_OFF 24576
#define K1_LDS 27648

__global__ __launch_bounds__(192, 4) void win_attn(
    const float* __restrict__ x,
    const float* __restrict__ qkv_b,
    const unsigned short* __restrict__ wq16,
    const float* __restrict__ bias_cd,
    float* __restrict__ outO)
{
    extern __shared__ char smem[];
    const int tid  = threadIdx.x;
    const int lane = tid & 63;
    const int wv   = tid >> 6;                 // wave in block: 0..2
    const int widx = blockIdx.x >> 1;          // window
    const int h    = (blockIdx.x & 1) * 3 + wv;// head
    const int l15  = lane & 15;
    const int quad = lane >> 4;

    // ---- stage x -> xs (bf16 frag-line layout, rows >=49 zero) ----
    #pragma unroll
    for (int i = 0; i < 8; ++i) {
        int c  = tid + i * 192;         // 1536 chunks = (ks*4+mt)*64 + cl
        int cl = c & 63;
        int mt = (c >> 6) & 3;
        int ks = c >> 8;
        int tok = mt * 16 + (cl & 15);
        int d0  = ks * 32 + (cl >> 4) * 8;
        uint4 o = {0u, 0u, 0u, 0u};
        if (tok < NTOK) {
            const float* p = x + ((size_t)widx * NTOK + tok) * DIM + d0;
            float4 a  = *(const float4*)p;
            float4 bb = *(const float4*)(p + 4);
            o.x = pack2(a.x, a.y); o.y = pack2(a.z, a.w);
            o.z = pack2(bb.x, bb.y); o.w = pack2(bb.z, bb.w);
        }
        *(uint4*)(smem + (size_t)c * 16) = o;
    }
    __syncthreads();                   // the ONLY barrier

    // hoisted bases
    char* const xrd = smem + lane * 16;                     // + (ks*4+nt)*1024
    char* const buf = smem + SCR_OFF + wv * 1024;           // 1KB per-wave scratch
    char* const swr = buf + (quad & 1) * 8 + l15 * 16 + (quad >> 1) * 256;  // + slot*512
    char* const srd = buf + lane * 16;
    const unsigned short* const wqh = wq16 + (size_t)(h * 128 + lane) * 8;  // q:+(ks*36+ft)*512, k:+6144, v:+12288

    // ---- q pass: C^T = Wq @ x^T (32 acc regs) ----
    int4 qf[4];
    {
        f32x4 qa[2][4];
        #pragma unroll
        for (int ft = 0; ft < 2; ++ft)
            #pragma unroll
            for (int nt = 0; nt < 4; ++nt) qa[ft][nt] = (f32x4){0,0,0,0};
        #pragma unroll
        for (int ks = 0; ks < 6; ++ks) {
            int4 wq[2];
            #pragma unroll
            for (int ft = 0; ft < 2; ++ft)
                wq[ft] = *(const int4*)(wqh + (ks*36 + ft) * 512);
            #pragma unroll
            for (int nt = 0; nt < 4; ++nt) {
                int4 xf = *(const int4*)(xrd + (ks*4 + nt) * 1024);
                #pragma unroll
                for (int ft = 0; ft < 2; ++ft)
                    qa[ft][nt] = mfma16(wq[ft], xf, qa[ft][nt]);
            }
        }
        float4 bq[2];
        #pragma unroll
        for (int ft = 0; ft < 2; ++ft) {
            float4 t = *(const float4*)(qkv_b + (h*2 + ft)*16 + quad*4);
            bq[ft].x = t.x*SCALE; bq[ft].y = t.y*SCALE; bq[ft].z = t.z*SCALE; bq[ft].w = t.w*SCALE;
        }
        #pragma unroll
        for (int nt = 0; nt < 4; ++nt) {
            #pragma unroll
            for (int ft = 0; ft < 2; ++ft) {
                uint2 w;
                w.x = pack2(qa[ft][nt][0] + bq[ft].x, qa[ft][nt][1] + bq[ft].y);
                w.y = pack2(qa[ft][nt][2] + bq[ft].z, qa[ft][nt][3] + bq[ft].w);
                *(uint2*)(swr + ft * 512) = w;
            }
            qf[nt] = *(const int4*)srd;
        }
    }

    // ---- k pass (reuses acc regs) ----
    int4 kf[4];
    {
        f32x4 ka[2][4];
        #pragma unroll
        for (int ft = 0; ft < 2; ++ft)
            #pragma unroll
            for (int nt = 0; nt < 4; ++nt) ka[ft][nt] = (f32x4){0,0,0,0};
        #pragma unroll
        for (int ks = 0; ks < 6; ++ks) {
            int4 wk[2];
            #pragma unroll
            for (int ft = 0; ft < 2; ++ft)
                wk[ft] = *(const int4*)(wqh + (ks*36 + ft) * 512 + 6144);
            #pragma unroll
            for (int nt = 0; nt < 4; ++nt) {
                int4 xf = *(const int4*)(xrd + (ks*4 + nt) * 1024);
                #pragma unroll
                for (int ft = 0; ft < 2; ++ft)
                    ka[ft][nt] = mfma16(wk[ft], xf, ka[ft][nt]);
            }
        }
        float4 bk[2];
        #pragma unroll
        for (int ft = 0; ft < 2; ++ft)
            bk[ft] = *(const float4*)(qkv_b + 192 + (h*2 + ft)*16 + quad*4);
        #pragma unroll
        for (int nt = 0; nt < 4; ++nt) {
            #pragma unroll
            for (int ft = 0; ft < 2; ++ft) {
                uint2 w;
                w.x = pack2(ka[ft][nt][0] + bk[ft].x, ka[ft][nt][1] + bk[ft].y);
                w.y = pack2(ka[ft][nt][2] + bk[ft].z, ka[ft][nt][3] + bk[ft].w);
                *(uint2*)(swr + ft * 512) = w;
            }
            kf[nt] = *(const int4*)srd;
        }
    }

    // ---- S^T = k @ q^T + bias^T, softmax over keys, streamed per qt ----
    float inv[4];
    int4 pf[2][4];
    const float* const bcb = bias_cd + (size_t)(h * 1024 + lane) * 4;  // + (kt*4+qt)*256 floats
    #pragma unroll
    for (int qt = 0; qt < 4; ++qt) {
        float sum = 0.f;
        #pragma unroll
        for (int ksn = 0; ksn < 2; ++ksn) {
            #pragma unroll
            for (int kt2 = 0; kt2 < 2; ++kt2) {
                const int kt = ksn*2 + kt2;
                f32x4 z = {0,0,0,0};
                f32x4 s = mfma16(kf[kt], qf[qt], z);
                float4 bc = *(const float4*)(bcb + (kt*4 + qt) * 256);
                // logits are O(1); padded keys carry -1e30 -> exp underflows to 0
                float e0 = __expf(s[0] + bc.x);
                float e1 = __expf(s[1] + bc.y);
                float e2 = __expf(s[2] + bc.z);
                float e3 = __expf(s[3] + bc.w);
                sum += (e0 + e1) + (e2 + e3);
                uint2 w;
                w.x = pack2(e0, e1);
                w.y = pack2(e2, e3);
                *(uint2*)(swr + kt2 * 512) = w;
            }
            pf[ksn][qt] = *(const int4*)srd;
        }
        sum += __shfl_xor(sum, 16);
        sum += __shfl_xor(sum, 32);
        inv[qt] = 1.0f / sum;                   // folded into O epilogue
    }

    // ---- v pass ----
    int4 vf[2][2];
    {
        f32x4 va[4][2];
        #pragma unroll
        for (int mt = 0; mt < 4; ++mt)
            #pragma unroll
            for (int nv = 0; nv < 2; ++nv) va[mt][nv] = (f32x4){0,0,0,0};
        #pragma unroll
        for (int ks = 0; ks < 6; ++ks) {
            int4 wvv[2];
            #pragma unroll
            for (int nv = 0; nv < 2; ++nv)
                wvv[nv] = *(const int4*)(wqh + (ks*36 + nv) * 512 + 12288);
            #pragma unroll
            for (int mt = 0; mt < 4; ++mt) {
                int4 xf = *(const int4*)(xrd + (ks*4 + mt) * 1024);
                #pragma unroll
                for (int nv = 0; nv < 2; ++nv)
                    va[mt][nv] = mfma16(xf, wvv[nv], va[mt][nv]);
            }
        }
        const float bv0 = qkv_b[384 + h*32 + l15];
        const float bv1 = qkv_b[384 + h*32 + 16 + l15];
        #pragma unroll
        for (int ksn = 0; ksn < 2; ++ksn) {
            #pragma unroll
            for (int nv = 0; nv < 2; ++nv) {
                const float bv = nv ? bv1 : bv0;
                #pragma unroll
                for (int mt2 = 0; mt2 < 2; ++mt2) {
                    const int mt = ksn*2 + mt2;
                    uint2 w;
                    w.x = pack2(va[mt][nv][0] + bv, va[mt][nv][1] + bv);
                    w.y = pack2(va[mt][nv][2] + bv, va[mt][nv][3] + bv);
                    *(uint2*)(swr + mt2 * 512) = w;
                }
                vf[ksn][nv] = *(const int4*)srd;
            }
        }
    }

    // ---- O^T = v^T @ P^T ----
    f32x4 oacc[2][4];                           // [dmt][qt]
    #pragma unroll
    for (int dmt = 0; dmt < 2; ++dmt)
        #pragma unroll
        for (int qt = 0; qt < 4; ++qt) oacc[dmt][qt] = (f32x4){0, 0, 0, 0};
    #pragma unroll
    for (int ksn = 0; ksn < 2; ++ksn)
        #pragma unroll
        for (int dmt = 0; dmt < 2; ++dmt)
            #pragma unroll
            for (int qt = 0; qt < 4; ++qt)
                oacc[dmt][qt] = mfma16(vf[ksn][dmt], pf[ksn][qt], oacc[dmt][qt]);

    // ---- epilogue: normalize, transpose to A-frag lines, park in out slice ----
    char* const og = (char*)outO + (size_t)widx * OUT_WIN_BYTES + (size_t)(h * 4) * 1024;
    #pragma unroll
    for (int qt = 0; qt < 4; ++qt) {
        uint2 w0, w1;
        w0.x = pack2(oacc[0][qt][0] * inv[qt], oacc[0][qt][1] * inv[qt]);
        w0.y = pack2(oacc[0][qt][2] * inv[qt], oacc[0][qt][3] * inv[qt]);
        *(uint2*)(swr + 0) = w0;
        w1.x = pack2(oacc[1][qt][0] * inv[qt], oacc[1][qt][1] * inv[qt]);
        w1.y = pack2(oacc[1][qt][2] * inv[qt], oacc[1][qt][3] * inv[qt]);
        *(uint2*)(swr + 512) = w1;
        int4 line = *(const int4*)srd;
        *(int4*)(og + qt * 1024 + lane * 16) = line;    // 1KB coalesced store
    }
}

// ---------- K2: out = O @ proj_w^T + proj_b (per window) ----------
#define K2_LDS 24576

__global__ __launch_bounds__(384, 5) void proj_k(
    float* __restrict__ out,
    const unsigned short* __restrict__ wp16,
    const float* __restrict__ proj_b)
{
    extern __shared__ char smem[];
    const int tid  = threadIdx.x;
    const int lane = tid & 63;
    const int h    = tid >> 6;
    const int l15  = lane & 15;
    const int quad = lane >> 4;
    const int widx = blockIdx.x;

    char* const base = (char*)out + (size_t)widx * OUT_WIN_BYTES;
    #pragma unroll
    for (int i = 0; i < 4; ++i) {
        int c = tid + i * 384;                  // 1536 chunks of 16B
        *(uint4*)(smem + (size_t)c * 16) = *(const uint4*)(base + (size_t)c * 16);
    }
    __syncthreads();                            // O staged; safe to overwrite slice

    char* const xrd = smem + lane * 16;
    const unsigned short* const wph = wp16 + (size_t)(h * 128 + lane) * 8;

    f32x4 acc[4][2];
    #pragma unroll
    for (int mt = 0; mt < 4; ++mt)
        #pragma unroll
        for (int j = 0; j < 2; ++j) acc[mt][j] = (f32x4){0, 0, 0, 0};
    #pragma unroll
    for (int ks = 0; ks < 6; ++ks) {
        int4 wb[2];
        #pragma unroll
        for (int j = 0; j < 2; ++j)
            wb[j] = *(const int4*)(wph + (ks*12 + j) * 512);
        #pragma unroll
        for (int mt = 0; mt < 4; ++mt) {
            int4 oa = *(const int4*)(xrd + (ks*4 + mt) * 1024);
            #pragma unroll
            for (int j = 0; j < 2; ++j)
                acc[mt][j] = mfma16(oa, wb[j], acc[mt][j]);
        }
    }
    #pragma unroll
    for (int j = 0; j < 2; ++j) {
        const int o = (h*2 + j) * 16 + l15;
        const float pb = proj_b[o];
        #pragma unroll
        for (int mt = 0; mt < 4; ++mt) {
            const int t0 = mt * 16 + quad * 4;
            #pragma unroll
            for (int r = 0; r < 4; ++r) {
                const int t = t0 + r;
                if (t < NTOK)
                    out[((size_t)widx * NTOK + t) * DIM + o] = acc[mt][j][r] + pb;
            }
        }
    }
}

extern "C" void kernel_launch(void* const* d_in, const int* in_sizes, int n_in,
                              void* d_out, int out_size, void* d_ws, size_t ws_size,
                              hipStream_t stream) {
    const float* x          = (const float*)d_in[0];
    const float* qkv_w      = (const float*)d_in[1];
    const float* qkv_b      = (const float*)d_in[2];
    const float* proj_w     = (const float*)d_in[3];
    const float* proj_b     = (const float*)d_in[4];
    const float* bias_table = (const float*)d_in[5];
    const int*   rel_index  = (const int*)d_in[6];
    float* out = (float*)d_out;

    unsigned short* w16 = (unsigned short*)d_ws;
    float* bias_cd = (float*)((char*)d_ws + BIAS_BYTE);

    prep<<<96, 256, 0, stream>>>(qkv_w, proj_w, bias_table, rel_index, w16, bias_cd);

    (void)hipFuncSetAttribute((const void*)win_attn,
                              hipFuncAttributeMaxDynamicSharedMemorySize, K1_LDS);
    win_attn<<<8192, 192, K1_LDS, stream>>>(x, qkv_b, w16, bias_cd, out);

    (void)hipFuncSetAttribute((const void*)proj_k,
                              hipFuncAttributeMaxDynamicSharedMemorySize, K2_LDS);
    proj_k<<<4096, 384, K2_LDS, stream>>>(out, w16 + WPROJ_USH, proj_b);
}

// Round 3
// 393.253 us; speedup vs baseline: 1.8678x; 1.7243x over previous
//
#include <hip/hip_runtime.h>

#define NTOK 49
#define DIM 192
#define HEADS 6

typedef __bf16 bf16x8 __attribute__((ext_vector_type(8)));
typedef float f32x4 __attribute__((ext_vector_type(4)));

// ws layout (bytes):
//   [0, 221184)        qkv_w bf16 frag-line layout (576 rows x 192, OT=36); q rows pre-scaled by 1/sqrt(32)
//   [221184, 294912)   proj_w bf16 frag layout (192 rows x 192, OT=12)
//   [294912, 393216)   bias_cd fp32 [6][16][64][4] in S^T C/D per-lane order
#define WPROJ_USH 110592
#define BIAS_BYTE 294912

#define SCALE 0.17677669529663687f   // 1/sqrt(32)

// O parking: window w's O lives in d_out's own slice: bytes [w*37632, w*37632+24576)
// as 24 bf16 A-frag lines of 1KB: line index (h*4 + qt), content = 64 lanes x 16B.
#define OUT_WIN_BYTES 37632          // 49*192*4

__device__ __forceinline__ unsigned int pack2(float a, float b) {
    unsigned short lo = __builtin_bit_cast(unsigned short, (__bf16)a);
    unsigned short hi = __builtin_bit_cast(unsigned short, (__bf16)b);
    return (unsigned int)lo | ((unsigned int)hi << 16);
}

__device__ __forceinline__ f32x4 mfma16(int4 a, int4 b, f32x4 c) {
    return __builtin_amdgcn_mfma_f32_16x16x32_bf16(
        __builtin_bit_cast(bf16x8, a), __builtin_bit_cast(bf16x8, b), c, 0, 0, 0);
}

// ---------- merged pre-kernel: weights + bias (unchanged layout) ----------
__global__ void prep(const float* __restrict__ qkv_w, const float* __restrict__ proj_w,
                     const float* __restrict__ bias_table, const int* __restrict__ rel_index,
                     unsigned short* __restrict__ w16, float* __restrict__ bias_cd) {
    int bid = blockIdx.x;
    if (bid < 72) {
        int c = bid * 256 + threadIdx.x;      // 16B chunk id, 0..18431
        const float* src; unsigned short* dst; int OT; int cc; int isq = 0;
        if (c < 13824)      { src = qkv_w;  dst = w16;             OT = 36; cc = c; isq = 1; }
        else                { src = proj_w; dst = w16 + WPROJ_USH; OT = 12; cc = c - 13824; }
        int lane = cc & 63;
        int t = cc >> 6;
        int ot = t % OT, ks = t / OT;
        int f  = ot * 16 + (lane & 15);
        int k0 = ks * 32 + (lane >> 4) * 8;
        float sc = (isq && f < 192) ? SCALE : 1.0f;   // fold softmax scale into q weights
        const float* p = src + (size_t)f * DIM + k0;
        float4 a = *(const float4*)p;
        float4 b = *(const float4*)(p + 4);
        uint4 o;
        o.x = pack2(a.x * sc, a.y * sc); o.y = pack2(a.z * sc, a.w * sc);
        o.z = pack2(b.x * sc, b.y * sc); o.w = pack2(b.z * sc, b.w * sc);
        *(uint4*)(dst + (size_t)cc * 8) = o;
    } else {
        int gid = (bid - 72) * 256 + threadIdx.x;     // 0..6143
        int lane = gid & 63;
        int tile = (gid >> 6) & 15;
        int h    = gid >> 10;
        int kt = tile >> 2, qt = tile & 3;            // S^T tile: m=key tile kt, n=qtok tile qt
        int qtok = qt * 16 + (lane & 15);
        int key0 = kt * 16 + (lane >> 4) * 4;
        float4 v;
        float* vp = (float*)&v;
        for (int r = 0; r < 4; ++r) {
            int key = key0 + r;
            float val;
            if (key >= NTOK)       val = -1e30f;      // padded key row -> softmax 0
            else if (qtok >= NTOK) val = 0.0f;        // padded query col: don't care
            else                   val = bias_table[rel_index[qtok * NTOK + key] * HEADS + h];
            vp[r] = val;
        }
        *(float4*)(bias_cd + (size_t)gid * 4) = v;
    }
}

// ---------- K1: attention. 1 block per window, 3 waves; each wave does 2 heads ----------
// LDS 27 KB: xs [0,24K) + per-wave 1KB scratch. ONE barrier; waves independent after.
// O written straight to global (window's own out slice) as bf16 A-frag lines.
// Bounds (192,2): 256-reg budget -> NO spill (r1/r2 lesson: tight bounds spill).
// Natural alloc ~110 -> 4 waves/SIMD by regs; LDS binds at 5 blocks = 15 waves/CU.
#define SCR_OFF 24576
#define K1_LDS 27648

__global__ __launch_bounds__(192, 2) void win_attn(
    const float* __restrict__ x,
    const float* __restrict__ qkv_b,
    const unsigned short* __restrict__ wq16,
    const float* __restrict__ bias_cd,
    float* __restrict__ outO)
{
    extern __shared__ char smem[];
    const int tid  = threadIdx.x;
    const int lane = tid & 63;
    const int wv   = tid >> 6;                 // wave in block: 0..2
    const int widx = blockIdx.x;               // window
    const int l15  = lane & 15;
    const int quad = lane >> 4;

    // ---- stage x -> xs once per window (bf16 frag-line layout, rows >=49 zero) ----
    #pragma unroll
    for (int i = 0; i < 8; ++i) {
        int c  = tid + i * 192;         // 1536 chunks = (ks*4+mt)*64 + cl
        int cl = c & 63;
        int mt = (c >> 6) & 3;
        int ks = c >> 8;
        int tok = mt * 16 + (cl & 15);
        int d0  = ks * 32 + (cl >> 4) * 8;
        uint4 o = {0u, 0u, 0u, 0u};
        if (tok < NTOK) {
            const float* p = x + ((size_t)widx * NTOK + tok) * DIM + d0;
            float4 a  = *(const float4*)p;
            float4 bb = *(const float4*)(p + 4);
            o.x = pack2(a.x, a.y); o.y = pack2(a.z, a.w);
            o.z = pack2(bb.x, bb.y); o.w = pack2(bb.z, bb.w);
        }
        *(uint4*)(smem + (size_t)c * 16) = o;
    }
    __syncthreads();                   // the ONLY barrier

    // hoisted bases (head-independent)
    char* const xrd = smem + lane * 16;                     // + (ks*4+nt)*1024
    char* const buf = smem + SCR_OFF + wv * 1024;           // 1KB per-wave scratch
    char* const swr = buf + (quad & 1) * 8 + l15 * 16 + (quad >> 1) * 256;  // + slot*512
    char* const srd = buf + lane * 16;

    // ---- two heads per wave, strictly sequential (contains register liveness) ----
    #pragma unroll 1
    for (int hi = 0; hi < 2; ++hi) {
        const int h = wv + hi * 3;
        const unsigned short* const wqh = wq16 + (size_t)(h * 128 + lane) * 8;  // q:+(ks*36+ft)*512, k:+6144, v:+12288
        const float* const bcb = bias_cd + (size_t)(h * 1024 + lane) * 4;       // + (kt*4+qt)*256 floats

        // ---- q pass: C^T = Wq @ x^T (32 acc regs) ----
        int4 qf[4];
        {
            f32x4 qa[2][4];
            #pragma unroll
            for (int ft = 0; ft < 2; ++ft)
                #pragma unroll
                for (int nt = 0; nt < 4; ++nt) qa[ft][nt] = (f32x4){0,0,0,0};
            #pragma unroll 2
            for (int ks = 0; ks < 6; ++ks) {
                int4 wq[2];
                #pragma unroll
                for (int ft = 0; ft < 2; ++ft)
                    wq[ft] = *(const int4*)(wqh + (ks*36 + ft) * 512);
                #pragma unroll
                for (int nt = 0; nt < 4; ++nt) {
                    int4 xf = *(const int4*)(xrd + (ks*4 + nt) * 1024);
                    #pragma unroll
                    for (int ft = 0; ft < 2; ++ft)
                        qa[ft][nt] = mfma16(wq[ft], xf, qa[ft][nt]);
                }
            }
            float4 bq[2];
            #pragma unroll
            for (int ft = 0; ft < 2; ++ft) {
                float4 t = *(const float4*)(qkv_b + (h*2 + ft)*16 + quad*4);
                bq[ft].x = t.x*SCALE; bq[ft].y = t.y*SCALE; bq[ft].z = t.z*SCALE; bq[ft].w = t.w*SCALE;
            }
            #pragma unroll
            for (int nt = 0; nt < 4; ++nt) {
                #pragma unroll
                for (int ft = 0; ft < 2; ++ft) {
                    uint2 w;
                    w.x = pack2(qa[ft][nt][0] + bq[ft].x, qa[ft][nt][1] + bq[ft].y);
                    w.y = pack2(qa[ft][nt][2] + bq[ft].z, qa[ft][nt][3] + bq[ft].w);
                    *(uint2*)(swr + ft * 512) = w;
                }
                qf[nt] = *(const int4*)srd;
            }
        }

        // ---- k pass (reuses acc regs) ----
        int4 kf[4];
        {
            f32x4 ka[2][4];
            #pragma unroll
            for (int ft = 0; ft < 2; ++ft)
                #pragma unroll
                for (int nt = 0; nt < 4; ++nt) ka[ft][nt] = (f32x4){0,0,0,0};
            #pragma unroll 2
            for (int ks = 0; ks < 6; ++ks) {
                int4 wk[2];
                #pragma unroll
                for (int ft = 0; ft < 2; ++ft)
                    wk[ft] = *(const int4*)(wqh + (ks*36 + ft) * 512 + 6144);
                #pragma unroll
                for (int nt = 0; nt < 4; ++nt) {
                    int4 xf = *(const int4*)(xrd + (ks*4 + nt) * 1024);
                    #pragma unroll
                    for (int ft = 0; ft < 2; ++ft)
                        ka[ft][nt] = mfma16(wk[ft], xf, ka[ft][nt]);
                }
            }
            float4 bk[2];
            #pragma unroll
            for (int ft = 0; ft < 2; ++ft)
                bk[ft] = *(const float4*)(qkv_b + 192 + (h*2 + ft)*16 + quad*4);
            #pragma unroll
            for (int nt = 0; nt < 4; ++nt) {
                #pragma unroll
                for (int ft = 0; ft < 2; ++ft) {
                    uint2 w;
                    w.x = pack2(ka[ft][nt][0] + bk[ft].x, ka[ft][nt][1] + bk[ft].y);
                    w.y = pack2(ka[ft][nt][2] + bk[ft].z, ka[ft][nt][3] + bk[ft].w);
                    *(uint2*)(swr + ft * 512) = w;
                }
                kf[nt] = *(const int4*)srd;
            }
        }

        // ---- S^T = k @ q^T + bias^T, softmax over keys, streamed per qt ----
        float inv[4];
        int4 pf[2][4];
        #pragma unroll
        for (int qt = 0; qt < 4; ++qt) {
            float sum = 0.f;
            #pragma unroll
            for (int ksn = 0; ksn < 2; ++ksn) {
                #pragma unroll
                for (int kt2 = 0; kt2 < 2; ++kt2) {
                    const int kt = ksn*2 + kt2;
                    f32x4 z = {0,0,0,0};
                    f32x4 s = mfma16(kf[kt], qf[qt], z);
                    float4 bc = *(const float4*)(bcb + (kt*4 + qt) * 256);
                    // logits are O(1); padded keys carry -1e30 -> exp underflows to 0
                    float e0 = __expf(s[0] + bc.x);
                    float e1 = __expf(s[1] + bc.y);
                    float e2 = __expf(s[2] + bc.z);
                    float e3 = __expf(s[3] + bc.w);
                    sum += (e0 + e1) + (e2 + e3);
                    uint2 w;
                    w.x = pack2(e0, e1);
                    w.y = pack2(e2, e3);
                    *(uint2*)(swr + kt2 * 512) = w;
                }
                pf[ksn][qt] = *(const int4*)srd;
            }
            sum += __shfl_xor(sum, 16);
            sum += __shfl_xor(sum, 32);
            inv[qt] = 1.0f / sum;                   // folded into O epilogue
        }

        // ---- v pass ----
        int4 vf[2][2];
        {
            f32x4 va[4][2];
            #pragma unroll
            for (int mt = 0; mt < 4; ++mt)
                #pragma unroll
                for (int nv = 0; nv < 2; ++nv) va[mt][nv] = (f32x4){0,0,0,0};
            #pragma unroll 2
            for (int ks = 0; ks < 6; ++ks) {
                int4 wvv[2];
                #pragma unroll
                for (int nv = 0; nv < 2; ++nv)
                    wvv[nv] = *(const int4*)(wqh + (ks*36 + nv) * 512 + 12288);
                #pragma unroll
                for (int mt = 0; mt < 4; ++mt) {
                    int4 xf = *(const int4*)(xrd + (ks*4 + mt) * 1024);
                    #pragma unroll
                    for (int nv = 0; nv < 2; ++nv)
                        va[mt][nv] = mfma16(xf, wvv[nv], va[mt][nv]);
                }
            }
            const float bv0 = qkv_b[384 + h*32 + l15];
            const float bv1 = qkv_b[384 + h*32 + 16 + l15];
            #pragma unroll
            for (int ksn = 0; ksn < 2; ++ksn) {
                #pragma unroll
                for (int nv = 0; nv < 2; ++nv) {
                    const float bv = nv ? bv1 : bv0;
                    #pragma unroll
                    for (int mt2 = 0; mt2 < 2; ++mt2) {
                        const int mt = ksn*2 + mt2;
                        uint2 w;
                        w.x = pack2(va[mt][nv][0] + bv, va[mt][nv][1] + bv);
                        w.y = pack2(va[mt][nv][2] + bv, va[mt][nv][3] + bv);
                        *(uint2*)(swr + mt2 * 512) = w;
                    }
                    vf[ksn][nv] = *(const int4*)srd;
                }
            }
        }

        // ---- O^T = v^T @ P^T ----
        f32x4 oacc[2][4];                           // [dmt][qt]
        #pragma unroll
        for (int dmt = 0; dmt < 2; ++dmt)
            #pragma unroll
            for (int qt = 0; qt < 4; ++qt) oacc[dmt][qt] = (f32x4){0, 0, 0, 0};
        #pragma unroll
        for (int ksn = 0; ksn < 2; ++ksn)
            #pragma unroll
            for (int dmt = 0; dmt < 2; ++dmt)
                #pragma unroll
                for (int qt = 0; qt < 4; ++qt)
                    oacc[dmt][qt] = mfma16(vf[ksn][dmt], pf[ksn][qt], oacc[dmt][qt]);

        // ---- epilogue: normalize, transpose to A-frag lines, park in out slice ----
        char* const og = (char*)outO + (size_t)widx * OUT_WIN_BYTES + (size_t)(h * 4) * 1024;
        #pragma unroll
        for (int qt = 0; qt < 4; ++qt) {
            uint2 w0, w1;
            w0.x = pack2(oacc[0][qt][0] * inv[qt], oacc[0][qt][1] * inv[qt]);
            w0.y = pack2(oacc[0][qt][2] * inv[qt], oacc[0][qt][3] * inv[qt]);
            *(uint2*)(swr + 0) = w0;
            w1.x = pack2(oacc[1][qt][0] * inv[qt], oacc[1][qt][1] * inv[qt]);
            w1.y = pack2(oacc[1][qt][2] * inv[qt], oacc[1][qt][3] * inv[qt]);
            *(uint2*)(swr + 512) = w1;
            int4 line = *(const int4*)srd;
            *(int4*)(og + qt * 1024 + lane * 16) = line;    // 1KB coalesced store
        }
    }
}

// ---------- K2: out = O @ proj_w^T + proj_b (per window) ----------
#define K2_LDS 24576

__global__ __launch_bounds__(384, 4) void proj_k(
    float* __restrict__ out,
    const unsigned short* __restrict__ wp16,
    const float* __restrict__ proj_b)
{
    extern __shared__ char smem[];
    const int tid  = threadIdx.x;
    const int lane = tid & 63;
    const int h    = tid >> 6;
    const int l15  = lane & 15;
    const int quad = lane >> 4;
    const int widx = blockIdx.x;

    char* const base = (char*)out + (size_t)widx * OUT_WIN_BYTES;
    #pragma unroll
    for (int i = 0; i < 4; ++i) {
        int c = tid + i * 384;                  // 1536 chunks of 16B
        *(uint4*)(smem + (size_t)c * 16) = *(const uint4*)(base + (size_t)c * 16);
    }
    __syncthreads();                            // O staged; safe to overwrite slice

    char* const xrd = smem + lane * 16;
    const unsigned short* const wph = wp16 + (size_t)(h * 128 + lane) * 8;

    f32x4 acc[4][2];
    #pragma unroll
    for (int mt = 0; mt < 4; ++mt)
        #pragma unroll
        for (int j = 0; j < 2; ++j) acc[mt][j] = (f32x4){0, 0, 0, 0};
    #pragma unroll 2
    for (int ks = 0; ks < 6; ++ks) {
        int4 wb[2];
        #pragma unroll
        for (int j = 0; j < 2; ++j)
            wb[j] = *(const int4*)(wph + (ks*12 + j) * 512);
        #pragma unroll
        for (int mt = 0; mt < 4; ++mt) {
            int4 oa = *(const int4*)(xrd + (ks*4 + mt) * 1024);
            #pragma unroll
            for (int j = 0; j < 2; ++j)
                acc[mt][j] = mfma16(oa, wb[j], acc[mt][j]);
        }
    }
    #pragma unroll
    for (int j = 0; j < 2; ++j) {
        const int o = (h*2 + j) * 16 + l15;
        const float pb = proj_b[o];
        #pragma unroll
        for (int mt = 0; mt < 4; ++mt) {
            const int t0 = mt * 16 + quad * 4;
            #pragma unroll
            for (int r = 0; r < 4; ++r) {
                const int t = t0 + r;
                if (t < NTOK)
                    out[((size_t)widx * NTOK + t) * DIM + o] = acc[mt][j][r] + pb;
            }
        }
    }
}

extern "C" void kernel_launch(void* const* d_in, const int* in_sizes, int n_in,
                              void* d_out, int out_size, void* d_ws, size_t ws_size,
                              hipStream_t stream) {
    const float* x          = (const float*)d_in[0];
    const float* qkv_w      = (const float*)d_in[1];
    const float* qkv_b      = (const float*)d_in[2];
    const float* proj_w     = (const float*)d_in[3];
    const float* proj_b     = (const float*)d_in[4];
    const float* bias_table = (const float*)d_in[5];
    const int*   rel_index  = (const int*)d_in[6];
    float* out = (float*)d_out;

    unsigned short* w16 = (unsigned short*)d_ws;
    float* bias_cd = (float*)((char*)d_ws + BIAS_BYTE);

    prep<<<96, 256, 0, stream>>>(qkv_w, proj_w, bias_table, rel_index, w16, bias_cd);

    (void)hipFuncSetAttribute((const void*)win_attn,
                              hipFuncAttributeMaxDynamicSharedMemorySize, K1_LDS);
    win_attn<<<4096, 192, K1_LDS, stream>>>(x, qkv_b, w16, bias_cd, out);

    (void)hipFuncSetAttribute((const void*)proj_k,
                              hipFuncAttributeMaxDynamicSharedMemorySize, K2_LDS);
    proj_k<<<4096, 384, K2_LDS, stream>>>(out, w16 + WPROJ_USH, proj_b);
}